// Round 1
// baseline (146.958 us; speedup 1.0000x reference)
//
#include <hip/hip_runtime.h>

// WaveletLoss: 3-level Haar DWT + soft-threshold + weighted mean-abs-diff.
// B=64, C=1, H=W=512. Each thread owns one 8x8 pixel block of one image;
// the full 3-level pyramid of that block is computed in registers.

#define IMG_H 512
#define IMG_W 512
#define N_BATCH 64

// thresholds: 50 / 2^(level-1) / 255
#define THR1 (50.0f / 255.0f)
#define THR2 (25.0f / 255.0f)
#define THR3 (12.5f / 255.0f)

// weights: 1 / (level * 3 * N_level),  N_l = 64 * (512/2^l)^2
__device__ __constant__ float c_unused; // (no constant state needed; weights are constexpr)

__device__ __forceinline__ float softthr(float x, float thr) {
    float m = fmaxf(fabsf(x) - thr, 0.0f);
    return copysignf(m, x);
}

__device__ __forceinline__ float detail_term(float p, float t, float thr) {
    return fabsf(softthr(p, thr) - softthr(t, thr));
}

__device__ __forceinline__ void haar_quad(float a, float b, float c, float d,
                                          float& cA, float& cH, float& cV, float& cD) {
    cA = 0.5f * (a + b + c + d);
    cH = 0.5f * (a + b - c - d);
    cV = 0.5f * (a - b + c - d);
    cD = 0.5f * (a - b - c + d);
}

__global__ void zero_out_kernel(float* out) { out[0] = 0.0f; }

__global__ __launch_bounds__(256)
void wavelet_loss_kernel(const float* __restrict__ pred,
                         const float* __restrict__ target,
                         float* __restrict__ out) {
    const int tid = blockIdx.x * 256 + threadIdx.x;
    // 64x64 blocks of 8x8 per image, 64 images
    const int b   = tid >> 12;        // /4096
    const int rem = tid & 4095;
    const int by  = rem >> 6;
    const int bx  = rem & 63;

    const long base = (long)b * (IMG_H * IMG_W) + (long)(by * 8) * IMG_W + bx * 8;

    float cA1p[16], cA1t[16];
    float s1 = 0.0f, s2 = 0.0f, s3 = 0.0f;

    // ---- level 1: four row-pairs of the 8x8 block ----
    #pragma unroll
    for (int rp = 0; rp < 4; ++rp) {
        const float* prA = pred + base + (2 * rp) * IMG_W;
        const float* prB = pred + base + (2 * rp + 1) * IMG_W;
        const float* trA = target + base + (2 * rp) * IMG_W;
        const float* trB = target + base + (2 * rp + 1) * IMG_W;

        float4 pA0 = *(const float4*)(prA);
        float4 pA1 = *(const float4*)(prA + 4);
        float4 pB0 = *(const float4*)(prB);
        float4 pB1 = *(const float4*)(prB + 4);
        float4 tA0 = *(const float4*)(trA);
        float4 tA1 = *(const float4*)(trA + 4);
        float4 tB0 = *(const float4*)(trB);
        float4 tB1 = *(const float4*)(trB + 4);

        float pa[4] = {pA0.x, pA0.z, pA1.x, pA1.z};
        float pb[4] = {pA0.y, pA0.w, pA1.y, pA1.w};
        float pc[4] = {pB0.x, pB0.z, pB1.x, pB1.z};
        float pd[4] = {pB0.y, pB0.w, pB1.y, pB1.w};
        float ta[4] = {tA0.x, tA0.z, tA1.x, tA1.z};
        float tb[4] = {tA0.y, tA0.w, tA1.y, tA1.w};
        float tc[4] = {tB0.x, tB0.z, tB1.x, tB1.z};
        float td[4] = {tB0.y, tB0.w, tB1.y, tB1.w};

        #pragma unroll
        for (int j = 0; j < 4; ++j) {
            float cAp, cHp, cVp, cDp, cAt, cHt, cVt, cDt;
            haar_quad(pa[j], pb[j], pc[j], pd[j], cAp, cHp, cVp, cDp);
            haar_quad(ta[j], tb[j], tc[j], td[j], cAt, cHt, cVt, cDt);
            s1 += detail_term(cHp, cHt, THR1)
                + detail_term(cVp, cVt, THR1)
                + detail_term(cDp, cDt, THR1);
            cA1p[rp * 4 + j] = cAp;
            cA1t[rp * 4 + j] = cAt;
        }
    }

    // ---- level 2: 4x4 cA1 -> 2x2 ----
    float cA2p[4], cA2t[4];
    #pragma unroll
    for (int i2 = 0; i2 < 2; ++i2) {
        #pragma unroll
        for (int j2 = 0; j2 < 2; ++j2) {
            int i = 2 * i2, j = 2 * j2;
            float cAp, cHp, cVp, cDp, cAt, cHt, cVt, cDt;
            haar_quad(cA1p[i * 4 + j], cA1p[i * 4 + j + 1],
                      cA1p[(i + 1) * 4 + j], cA1p[(i + 1) * 4 + j + 1],
                      cAp, cHp, cVp, cDp);
            haar_quad(cA1t[i * 4 + j], cA1t[i * 4 + j + 1],
                      cA1t[(i + 1) * 4 + j], cA1t[(i + 1) * 4 + j + 1],
                      cAt, cHt, cVt, cDt);
            s2 += detail_term(cHp, cHt, THR2)
                + detail_term(cVp, cVt, THR2)
                + detail_term(cDp, cDt, THR2);
            cA2p[i2 * 2 + j2] = cAp;
            cA2t[i2 * 2 + j2] = cAt;
        }
    }

    // ---- level 3: 2x2 cA2 -> 1 ----
    {
        float cAp, cHp, cVp, cDp, cAt, cHt, cVt, cDt;
        haar_quad(cA2p[0], cA2p[1], cA2p[2], cA2p[3], cAp, cHp, cVp, cDp);
        haar_quad(cA2t[0], cA2t[1], cA2t[2], cA2t[3], cAt, cHt, cVt, cDt);
        s3 += detail_term(cHp, cHt, THR3)
            + detail_term(cVp, cVt, THR3)
            + detail_term(cDp, cDt, THR3);
    }

    // weights: 1/(level * 3 * N_level)
    constexpr float W1 = 1.0f / (1.0f * 3.0f * (float)(N_BATCH * 256 * 256));
    constexpr float W2 = 1.0f / (2.0f * 3.0f * (float)(N_BATCH * 128 * 128));
    constexpr float W3 = 1.0f / (3.0f * 3.0f * (float)(N_BATCH * 64 * 64));

    float v = W1 * s1 + W2 * s2 + W3 * s3;

    // wave (64-lane) reduction
    #pragma unroll
    for (int off = 32; off > 0; off >>= 1)
        v += __shfl_down(v, off, 64);

    __shared__ float wave_sums[4];
    const int lane = threadIdx.x & 63;
    const int wave = threadIdx.x >> 6;
    if (lane == 0) wave_sums[wave] = v;
    __syncthreads();
    if (threadIdx.x == 0) {
        float s = wave_sums[0] + wave_sums[1] + wave_sums[2] + wave_sums[3];
        atomicAdd(out, s);
    }
}

extern "C" void kernel_launch(void* const* d_in, const int* in_sizes, int n_in,
                              void* d_out, int out_size, void* d_ws, size_t ws_size,
                              hipStream_t stream) {
    const float* pred   = (const float*)d_in[0];
    const float* target = (const float*)d_in[1];
    float* out = (float*)d_out;

    zero_out_kernel<<<1, 1, 0, stream>>>(out);

    // 64 images * 64*64 blocks = 262144 threads = 1024 blocks of 256
    wavelet_loss_kernel<<<1024, 256, 0, stream>>>(pred, target, out);
}